// Round 6
// baseline (11.832 us; speedup 1.0000x reference)
//
#include <hip/hip_runtime.h>
#include <cmath>

#define ETA_INV 1.0526315789473684f   // 1/0.95

struct In9 { float p_g, p_p, p_s, p_c, p_d, dt, C0, C1, C2; };

__device__ __forceinline__ In9 load9(
    const float* __restrict__ pi_g, const float* __restrict__ pi_p,
    const float* __restrict__ pi_s, const float* __restrict__ pi_c,
    const float* __restrict__ pi_d, const float* __restrict__ d_t,
    const float* __restrict__ C, int inst, int tc)
{
    In9 v;
    const size_t b24 = (size_t)inst * 24 + tc;
    v.p_g = pi_g[b24];
    v.p_p = pi_p[b24];
    v.p_s = pi_s[b24];
    v.p_c = pi_c[b24];
    v.p_d = pi_d[b24];
    v.dt  = d_t[b24];
    const size_t b72 = (size_t)inst * 72 + 3 * tc;
    v.C0 = C[b72]; v.C1 = C[b72 + 1]; v.C2 = C[b72 + 2];
    return v;
}

// Per-instance compute on one 32-lane group (lane t = time slot); round-5 math.
__device__ __forceinline__ void compute_store(In9 v, int t, bool act, int inst,
                                              float* __restrict__ out)
{
    float p_g = v.p_g;
    float p_p = fmaxf(v.p_p, 0.f);
    float p_s = fmaxf(v.p_s, 0.f);
    float p_c = fmaxf(v.p_c, 0.f);
    float p_d = fmaxf(v.p_d, 0.f);
    float dt  = v.dt;
    float C0 = v.C0, C1 = v.C1, C2 = v.C2;

    // scan 1: exclusive prefix sum of pi_s/eta
    float ps_eta = p_s * ETA_INV;
    float cs = __shfl_up(ps_eta, 1, 32);
    if (t == 0) cs = 0.f;
#pragma unroll
    for (int off = 1; off < 32; off <<= 1) {
        float o = __shfl_up(cs, off, 32);
        if (t >= off) cs += o;
    }

    // scan 2: online-softmax (m,S) inclusive scan, single-exp combine
    float gt = -5.f * (p_c * (ETA_INV * ETA_INV) + p_g - cs);
    float m = gt, S = 1.f;
#pragma unroll
    for (int off = 1; off < 32; off <<= 1) {
        float mo = __shfl_up(m, off, 32);
        float So = __shfl_up(S, off, 32);
        if (t >= off) {
            float e = __expf(-fabsf(m - mo));
            bool mge = (m >= mo);
            S = mge ? (S + So * e) : (S * e + So);
            m = mge ? m : mo;
        }
    }
    float m_ex = __shfl_up(m, 1, 32);
    float S_ex = __shfl_up(S, 1, 32);
    if (t == 0) { m_ex = -1e30f; S_ex = 0.f; }

    // cascade (per-lane)
    float pi_t = cs - 0.2f * m_ex;                 // t=0 -> ~2e29 acts as +inf
    float X0 = pi_t + p_d * ETA_INV;
    float y0 = -10.f * X0, y1 = -10.f * p_p, y2 = -10.f * p_g;

    float mx1 = fmaxf(fmaxf(y0, y1), y2);
    float e0 = __expf(y0 - mx1), e1 = __expf(y1 - mx1), e2 = __expf(y2 - mx1);
    float rs1 = 1.0f / (e0 + e1 + e2);
    float a10 = e0 * rs1, a11 = e1 * rs1, a12 = e2 * rs1;

    float z0 = y0 - 10000.f * a10, z1 = y1 - 10000.f * a11, z2 = y2 - 10000.f * a12;
    float mx2 = fmaxf(fmaxf(z0, z1), z2);
    float f0 = __expf(z0 - mx2), f1 = __expf(z1 - mx2), f2 = __expf(z2 - mx2);
    float rs2 = 1.0f / (f0 + f1 + f2);
    float a20 = f0 * rs2, a21 = f1 * rs2, a22 = f2 * rs2;

    float w0_ = z0 - 10000.f * a20, w1_ = z1 - 10000.f * a21, w2_ = z2 - 10000.f * a22;
    float mx3 = fmaxf(fmaxf(w0_, w1_), w2_);
    float h0 = __expf(w0_ - mx3), h1 = __expf(w1_ - mx3), h2 = __expf(w2_ - mx3);
    float rs3 = 1.0f / (h0 + h1 + h2);
    float a30 = h0 * rs3, a31 = h1 * rs3, a32 = h2 * rs3;

    // demand breakup
    float delta0 = a10 * C0 + a11 * C1 + a12 * C2;
    float d0 = delta0 - fmaxf(delta0 - dt, 0.f);
    float delta1 = a20 * C0 + a21 * C1 + a22 * C2;
    float d1 = delta1 - fmaxf(delta1 - (dt - d0), 0.f);
    float delta2 = a30 * C0 + a31 * C1 + a32 * C2;
    float d2 = delta2 - fmaxf(delta2 - (dt - d0 - d1), 0.f);

    float dg = a12 * d0 + a22 * d1 + a32 * d2;
    float dp = a11 * d0 + a21 * d1 + a31 * d2;
    float dd = (a10 * d0 + a20 * d1 + a30 * d2) * ETA_INV;

    float rsv = (t == 0) ? 0.f : dd / S_ex;

    // scan 3: suffix scan of affine maps qs_i = A_i + B_i * qs_{i+1}
    float A  = __shfl_down(rsv, 1, 32);
    float mn = __shfl_down(m, 1, 32);
    float Bc = __expf(m - mn);               // <= 1 (m nondecreasing)
    if (t >= 23) { A = 0.f; Bc = 1.f; }
#pragma unroll
    for (int off = 1; off < 32; off <<= 1) {
        float Ao = __shfl_down(A, off, 32);
        float Bo = __shfl_down(Bc, off, 32);
        if (t + off < 23) { A = A + Bc * Ao; Bc = Bc * Bo; }
    }
    float qs = A;

    float dc = __expf(gt - m) * qs * ETA_INV;
    float ds = S * qs;

    if (act) {
        float* ob = out + (size_t)inst * 120 + t;
        ob[0]  = dg + dc;
        ob[24] = dp;
        ob[48] = ds;
        ob[72] = dc;
        ob[96] = dd;
    }
}

// 2 instances per thread: both loads issued up-front (memory latency of the
// second hides under the first's compute), then two compute+store phases.
__global__ __launch_bounds__(256, 4) void gru_kernel(
    const float* __restrict__ pi_g, const float* __restrict__ pi_p,
    const float* __restrict__ pi_s, const float* __restrict__ pi_c,
    const float* __restrict__ pi_d, const float* __restrict__ d_t,
    const float* __restrict__ C,    float* __restrict__ out,
    int nGrp, int nInst)
{
    const int g = blockIdx.x * 8 + (threadIdx.x >> 5);
    const int t = threadIdx.x & 31;
    if (g >= nGrp) return;
    const bool act = (t < 24);
    const int tc = act ? t : 23;

    In9 a = load9(pi_g, pi_p, pi_s, pi_c, pi_d, d_t, C, g, tc);
    const int g2 = g + nGrp;
    const bool has2 = (g2 < nInst);          // wave-uniform
    In9 b;
    if (has2) b = load9(pi_g, pi_p, pi_s, pi_c, pi_d, d_t, C, g2, tc);

    compute_store(a, t, act, g, out);
    if (has2) compute_store(b, t, act, g2, out);
}

extern "C" void kernel_launch(void* const* d_in, const int* in_sizes, int n_in,
                              void* d_out, int out_size, void* d_ws, size_t ws_size,
                              hipStream_t stream) {
    const float* pi_g = (const float*)d_in[0];
    const float* pi_p = (const float*)d_in[1];
    const float* pi_s = (const float*)d_in[2];
    const float* pi_c = (const float*)d_in[3];
    const float* pi_d = (const float*)d_in[4];
    const float* d_t  = (const float*)d_in[5];
    const float* C_t  = (const float*)d_in[6];
    float* out = (float*)d_out;

    int n = in_sizes[0] / 24;                 // batch = 16384 instances
    int nGrp = (n + 1) / 2;                   // first-half groups (second = g + nGrp)
    int blocks = (nGrp + 7) / 8;              // 8 groups per 256-thread block
    gru_kernel<<<blocks, 256, 0, stream>>>(pi_g, pi_p, pi_s, pi_c, pi_d, d_t, C_t,
                                           out, nGrp, n);
}

// Round 7
// 11.012 us; speedup vs baseline: 1.0745x; 1.0745x over previous
//
#include <hip/hip_runtime.h>
#include <cmath>

#define ETA_INV 1.0526315789473684f   // 1/0.95

// One 32-lane group per instance; lane t in [0,24) handles time slot t.
// All per-t scans done with width-32 wave shuffles; no LDS, no barriers.
// __launch_bounds__(256,8): force <=64 VGPR -> 8 waves/SIMD for latency hiding.
// NOTE (round 6): best measured config. 2-inst/thread ILP variant regressed
// (11.05 -> 11.83 us); kernel is pinned at ~7-8 us fixed launch overhead +
// ~3-4 us work, so body-level changes are null. Keep this shape.
__global__ __launch_bounds__(256, 8) void gru_kernel(
    const float* __restrict__ pi_g, const float* __restrict__ pi_p,
    const float* __restrict__ pi_s, const float* __restrict__ pi_c,
    const float* __restrict__ pi_d, const float* __restrict__ d_t,
    const float* __restrict__ C,    float* __restrict__ out, int nInst)
{
    const int inst = blockIdx.x * 8 + (threadIdx.x >> 5);
    const int t    = threadIdx.x & 31;
    if (inst >= nInst) return;
    const bool act = (t < 24);

    // ---- loads (lanes 24-31 clamp to t=23; their values never escape) ----
    const int tc = act ? t : 23;
    const size_t b24 = (size_t)inst * 24 + tc;
    float p_g = pi_g[b24];
    float p_p = fmaxf(pi_p[b24], 0.f);
    float p_s = fmaxf(pi_s[b24], 0.f);
    float p_c = fmaxf(pi_c[b24], 0.f);
    float p_d = fmaxf(pi_d[b24], 0.f);
    float dt  = d_t[b24];
    const size_t b72 = (size_t)inst * 72 + 3 * tc;
    float C0 = C[b72], C1 = C[b72 + 1], C2 = C[b72 + 2];

    // ---- scan 1: cs[t] = sum_{k<t} pi_s_eta[k]  (shift + inclusive sum) ----
    float ps_eta = p_s * ETA_INV;
    float cs = __shfl_up(ps_eta, 1, 32);
    if (t == 0) cs = 0.f;
#pragma unroll
    for (int off = 1; off < 32; off <<= 1) {
        float o = __shfl_up(cs, off, 32);
        if (t >= off) cs += o;
    }

    // ---- g[t]; scan 2: online-softmax pair (m,S) inclusive scan.
    //      nm = max(m,mo) => one exp is always 1: single-exp combine. ----
    float gt = -5.f * (p_c * (ETA_INV * ETA_INV) + p_g - cs);
    float m = gt, S = 1.f;
#pragma unroll
    for (int off = 1; off < 32; off <<= 1) {
        float mo = __shfl_up(m, off, 32);
        float So = __shfl_up(S, off, 32);
        if (t >= off) {
            float e = __expf(-fabsf(m - mo));      // exp of the loser's deficit
            bool mge = (m >= mo);
            S = mge ? (S + So * e) : (S * e + So);
            m = mge ? m : mo;
        }
    }
    float m_ex = __shfl_up(m, 1, 32);   // exclusive prefix max of g
    float S_ex = __shfl_up(S, 1, 32);   // exclusive scaled sum (at scale m_ex)
    if (t == 0) { m_ex = -1e30f; S_ex = 0.f; }

    // ---- cascade (per-lane, independent) ----
    float pi_t = cs - 0.2f * m_ex;                 // t=0 -> ~2e29 acts as +inf
    float X0 = pi_t + p_d * ETA_INV;
    float y0 = -10.f * X0, y1 = -10.f * p_p, y2 = -10.f * p_g;

    float mx1 = fmaxf(fmaxf(y0, y1), y2);
    float e0 = __expf(y0 - mx1), e1 = __expf(y1 - mx1), e2 = __expf(y2 - mx1);
    float rs1 = 1.0f / (e0 + e1 + e2);
    float a10 = e0 * rs1, a11 = e1 * rs1, a12 = e2 * rs1;

    float z0 = y0 - 10000.f * a10, z1 = y1 - 10000.f * a11, z2 = y2 - 10000.f * a12;
    float mx2 = fmaxf(fmaxf(z0, z1), z2);
    float f0 = __expf(z0 - mx2), f1 = __expf(z1 - mx2), f2 = __expf(z2 - mx2);
    float rs2 = 1.0f / (f0 + f1 + f2);
    float a20 = f0 * rs2, a21 = f1 * rs2, a22 = f2 * rs2;

    float w0_ = z0 - 10000.f * a20, w1_ = z1 - 10000.f * a21, w2_ = z2 - 10000.f * a22;
    float mx3 = fmaxf(fmaxf(w0_, w1_), w2_);
    float h0 = __expf(w0_ - mx3), h1 = __expf(w1_ - mx3), h2 = __expf(w2_ - mx3);
    float rs3 = 1.0f / (h0 + h1 + h2);
    float a30 = h0 * rs3, a31 = h1 * rs3, a32 = h2 * rs3;

    // ---- demand breakup (per-lane) ----
    float delta0 = a10 * C0 + a11 * C1 + a12 * C2;
    float d0 = delta0 - fmaxf(delta0 - dt, 0.f);
    float delta1 = a20 * C0 + a21 * C1 + a22 * C2;
    float d1 = delta1 - fmaxf(delta1 - (dt - d0), 0.f);
    float delta2 = a30 * C0 + a31 * C1 + a32 * C2;
    float d2 = delta2 - fmaxf(delta2 - (dt - d0 - d1), 0.f);

    float dg = a12 * d0 + a22 * d1 + a32 * d2;
    float dp = a11 * d0 + a21 * d1 + a31 * d2;
    float dd = (a10 * d0 + a20 * d1 + a30 * d2) * ETA_INV;

    float rs = (t == 0) ? 0.f : dd / S_ex;   // scaled r[t]; row 0 of i_t is zero

    // ---- scan 3: suffix scan of affine maps qs_i = A_i + B_i * qs_{i+1} ----
    float A  = __shfl_down(rs, 1, 32);       // rs[t+1]
    float mn = __shfl_down(m, 1, 32);        // m_in[t+1]
    float Bc = __expf(m - mn);               // <= 1 (m nondecreasing)
    if (t >= 23) { A = 0.f; Bc = 1.f; }      // identity maps at/after the tail
#pragma unroll
    for (int off = 1; off < 32; off <<= 1) {
        float Ao = __shfl_down(A, off, 32);
        float Bo = __shfl_down(Bc, off, 32);
        if (t + off < 23) { A = A + Bc * Ao; Bc = Bc * Bo; }
    }
    float qs = A;                            // = sum_{u>t} r_u * e^{m[t]-m[u-1]}

    float dc = __expf(gt - m) * qs * ETA_INV;  // exponent <= 0
    float ds = S * qs;

    // ---- stores: out[inst*120 + row*24 + t] ----
    if (act) {
        float* ob = out + (size_t)inst * 120 + t;
        ob[0]  = dg + dc;
        ob[24] = dp;
        ob[48] = ds;
        ob[72] = dc;
        ob[96] = dd;
    }
}

extern "C" void kernel_launch(void* const* d_in, const int* in_sizes, int n_in,
                              void* d_out, int out_size, void* d_ws, size_t ws_size,
                              hipStream_t stream) {
    const float* pi_g = (const float*)d_in[0];
    const float* pi_p = (const float*)d_in[1];
    const float* pi_s = (const float*)d_in[2];
    const float* pi_c = (const float*)d_in[3];
    const float* pi_d = (const float*)d_in[4];
    const float* d_t  = (const float*)d_in[5];
    const float* C_t  = (const float*)d_in[6];
    float* out = (float*)d_out;

    int n = in_sizes[0] / 24;                 // batch = 16384 instances
    int blocks = (n + 7) / 8;                 // 8 instances per 256-thread block
    gru_kernel<<<blocks, 256, 0, stream>>>(pi_g, pi_p, pi_s, pi_c, pi_d, d_t, C_t, out, n);
}